// Round 2
// baseline (112.422 us; speedup 1.0000x reference)
//
#include <hip/hip_runtime.h>

#define NB 4
#define NP 8
#define NV 2048
#define NE 2048
#define NF 4096
#define BIGV 1.0e10f
#define NCHUNK 8              // edge chunks per (b,p) combo
#define NCOMBO (NB * NP)      // 32

// ws layout:
//   minpart[combo][echunk][NV]  : 32*8*2048 floats = 2 MB   (partial mins + |pt|^2 folded back in)
//   volpart[64]                 : per-(b,facechunk) volume partial sums
#define MINPART_FLOATS (NCOMBO * NCHUNK * NV)

// K1: blocks [0,256): chamfer partial mins, 32 combos x 8 edge-chunks. Plain stores, no atomics.
//     blocks [256,320): volume face partial sums, 4 b x 16 face-chunks.
__global__ __launch_bounds__(256) void fused_k1(
    const float* __restrict__ xs, const float* __restrict__ pm,
    const float* __restrict__ edgemaps, const int* __restrict__ elen,
    const int* __restrict__ faces, float* __restrict__ minpart,
    float* __restrict__ volpart)
{
    __shared__ float4 eds[256];
    __shared__ float red[4];
    const int tid = threadIdx.x;
    const int bid = blockIdx.x;

    if (bid < 256) {
        const int combo  = bid >> 3;   // b*8 + p
        const int echunk = bid & 7;
        const int b = combo >> 3;
        const int p = combo & 7;

        // Stage this block's 256-edge chunk into LDS with validity masking.
        const int e   = (echunk << 8) + tid;
        const int len = elen[combo];
        float ex = edgemaps[((size_t)combo * NE + e) * 2 + 0];
        float ey = edgemaps[((size_t)combo * NE + e) * 2 + 1];
        float e2;
        if (e < len) {
            e2 = ex * ex + ey * ey;
        } else {
            ex = 0.0f; ey = 0.0f; e2 = BIGV;   // matches ref: d2 -> BIG for invalid e
        }
        eds[tid] = make_float4(ex, ey, e2, 0.0f);

        // Projection matrix for this p (uniform -> scalar loads).
        const float* M = pm + p * 12;
        const float m00 = M[0], m01 = M[1], m02 = M[2],  m03 = M[3];
        const float m10 = M[4], m11 = M[5], m12 = M[6],  m13 = M[7];
        const float m20 = M[8], m21 = M[9], m22 = M[10], m23 = M[11];

        // Each thread owns 8 vertices (v = tid + i*256): project once.
        float px2[8], py2[8], v2[8], mn[8];
        #pragma unroll
        for (int i = 0; i < 8; i++) {
            const int v = tid + (i << 8);
            const float x = xs[((size_t)b * NV + v) * 3 + 0];
            const float y = xs[((size_t)b * NV + v) * 3 + 1];
            const float z = xs[((size_t)b * NV + v) * 3 + 2];
            const float r0 = m00 * x + m01 * y + m02 * z + m03;
            const float r1 = m10 * x + m11 * y + m12 * z + m13;
            const float r2 = m20 * x + m21 * y + m22 * z + m23;
            const float inv = 1.0f / r2;       // r2 ~ 2.0 by construction
            const float px = r0 * inv;
            const float py = r1 * inv;
            px2[i] = -2.0f * px;
            py2[i] = -2.0f * py;
            v2[i]  = px * px + py * py;        // folded out of the min, added back at end
            mn[i]  = 3.0e38f;
        }
        __syncthreads();

        // Hot loop: 256 edges x 8 vertices, 3 VALU/pair (2 fma + min).
        #pragma unroll 4
        for (int k = 0; k < 256; k++) {
            const float4 ed = eds[k];
            #pragma unroll
            for (int i = 0; i < 8; i++)
                mn[i] = fminf(mn[i], fmaf(py2[i], ed.y, fmaf(px2[i], ed.x, ed.z)));
        }

        // Plain coalesced stores of this chunk's partial mins (k2 min-reduces the 8 chunks).
        float* dst = minpart + ((size_t)(combo * NCHUNK + echunk)) * NV;
        #pragma unroll
        for (int i = 0; i < 8; i++)
            dst[tid + (i << 8)] = mn[i] + v2[i];
    } else {
        // Volume: one face per thread, partial sum per block (no atomics).
        const int j = bid - 256;           // 0..63
        const int b = j >> 4;
        const int f = ((j & 15) << 8) + tid;
        const int* fc = faces + ((size_t)b * NF + f) * 3;
        const int i0 = fc[0], i1 = fc[1], i2 = fc[2];
        const float* xb = xs + (size_t)b * NV * 3;
        const float ax = xb[i0 * 3 + 0], ay = xb[i0 * 3 + 1], az = xb[i0 * 3 + 2];
        const float bx = xb[i1 * 3 + 0], by = xb[i1 * 3 + 1], bz = xb[i1 * 3 + 2];
        const float cx = xb[i2 * 3 + 0], cy = xb[i2 * 3 + 1], cz = xb[i2 * 3 + 2];
        const float crx = ay * bz - az * by;
        const float cry = az * bx - ax * bz;
        const float crz = ax * by - ay * bx;
        float fv = (crx * cx + cry * cy + crz * cz) * (1.0f / 6.0f);

        #pragma unroll
        for (int off = 32; off > 0; off >>= 1) fv += __shfl_down(fv, off);
        const int lane = tid & 63, w = tid >> 6;
        if (lane == 0) red[w] = fv;
        __syncthreads();
        if (tid == 0) volpart[j] = red[0] + red[1] + red[2] + red[3];
    }
}

// K2: one block per b; wave w owns projections 2w, 2w+1 end-to-end (no per-p syncs).
__global__ __launch_bounds__(256) void fused_k2(
    const float* __restrict__ minpart, const void* __restrict__ maskp,
    const float* __restrict__ volpart, const float* __restrict__ tv,
    float* __restrict__ out)
{
    __shared__ float acc[4];
    const int tid = threadIdx.x;
    const int lane = tid & 63, w = tid >> 6;
    const int b = blockIdx.x;

    // Sniff boundary_mask dtype: int32 0/1 words are <=1; packed 1-byte bools
    // read as words exceed 1 with overwhelming probability over 16 words.
    const int* mi = (const int*)maskp;
    const unsigned char* mb = (const unsigned char*)maskp;
    bool as_int = true;
    #pragma unroll
    for (int k = 0; k < 16; k++)
        if (((const unsigned*)maskp)[k] > 1u) as_int = false;

    float accum = 0.0f;
    #pragma unroll
    for (int pp = 0; pp < 2; pp++) {
        const int p = (w << 1) + pp;
        const int combo = b * NP + p;
        const float* base = minpart + (size_t)combo * NCHUNK * NV;
        float s = 0.0f, c = 0.0f;
        #pragma unroll 4
        for (int i = 0; i < 32; i++) {
            const int v = lane + (i << 6);
            float m = base[v];
            #pragma unroll
            for (int ch = 1; ch < NCHUNK; ch++)
                m = fminf(m, base[ch * NV + v]);
            const size_t mix = (size_t)combo * NV + v;
            const float msk = as_int ? (mi[mix] ? 1.0f : 0.0f)
                                     : (mb[mix] ? 1.0f : 0.0f);
            s += m * msk;
            c += msk;
        }
        #pragma unroll
        for (int off = 32; off > 0; off >>= 1) {
            s += __shfl_down(s, off);
            c += __shfl_down(c, off);
        }
        if (lane == 0) accum += s / fmaxf(c, 1.0f);
    }
    if (lane == 0) acc[w] = accum;
    __syncthreads();
    if (tid == 0) {
        out[b] = (acc[0] + acc[1] + acc[2] + acc[3]) * (1.0f / NP);
        float vs = 0.0f;
        #pragma unroll
        for (int k = 0; k < 16; k++) vs += volpart[b * 16 + k];
        const float d = fabsf(vs) - tv[b];
        out[4 + b] = d * d;
    }
}

extern "C" void kernel_launch(void* const* d_in, const int* in_sizes, int n_in,
                              void* d_out, int out_size, void* d_ws, size_t ws_size,
                              hipStream_t stream)
{
    const float* xs       = (const float*)d_in[0];
    const float* pm       = (const float*)d_in[1];
    const float* edgemaps = (const float*)d_in[2];
    const int*   elen     = (const int*)d_in[3];
    const void*  mask     = d_in[4];
    const int*   faces    = (const int*)d_in[5];
    const float* tv       = (const float*)d_in[6];
    float* out = (float*)d_out;

    float* minpart = (float*)d_ws;                          // 2 MB of partial mins
    float* volpart = minpart + MINPART_FLOATS;              // 64 floats

    fused_k1<<<dim3(320), dim3(256), 0, stream>>>(xs, pm, edgemaps, elen, faces, minpart, volpart);
    fused_k2<<<dim3(NB), dim3(256), 0, stream>>>(minpart, mask, volpart, tv, out);
}

// Round 3
// 84.482 us; speedup vs baseline: 1.3307x; 1.3307x over previous
//
#include <hip/hip_runtime.h>

#define NB 4
#define NP 8
#define NV 2048
#define NE 2048
#define NF 4096
#define BIGV 1.0e10f
#define NCHUNK 16             // edge chunks per (b,p) combo (128 edges each)
#define ECHUNK 128
#define NCOMBO (NB * NP)      // 32

// ws layout:
//   minpart[combo][echunk][NV] : 32*16*2048 floats = 4 MB (partial mins, |pt|^2 folded in)
//   volpart[64]                : per-(b,facechunk) volume partial sums
//   percombo[32]               : per-(b,p) masked means
#define MINPART_FLOATS (NCOMBO * NCHUNK * NV)

// K1: blocks [0,512): chamfer partial mins, 32 combos x 16 edge-chunks of 128.
//     blocks [512,576): volume face partial sums, 4 b x 16 face-chunks.
__global__ __launch_bounds__(256) void fused_k1(
    const float* __restrict__ xs, const float* __restrict__ pm,
    const float* __restrict__ edgemaps, const int* __restrict__ elen,
    const int* __restrict__ faces, float* __restrict__ minpart,
    float* __restrict__ volpart)
{
    __shared__ float4 eds[ECHUNK];
    __shared__ float red[4];
    const int tid = threadIdx.x;
    const int bid = blockIdx.x;

    if (bid < 512) {
        const int combo  = bid >> 4;   // b*8 + p
        const int echunk = bid & 15;
        const int b = combo >> 3;
        const int p = combo & 7;

        // Stage this block's 128-edge chunk into LDS (threads 0-127).
        if (tid < ECHUNK) {
            const int e   = echunk * ECHUNK + tid;
            const int len = elen[combo];
            float ex = edgemaps[((size_t)combo * NE + e) * 2 + 0];
            float ey = edgemaps[((size_t)combo * NE + e) * 2 + 1];
            float e2;
            if (e < len) {
                e2 = ex * ex + ey * ey;
            } else {
                ex = 0.0f; ey = 0.0f; e2 = BIGV;   // ref: d2 -> BIG for invalid e
            }
            eds[tid] = make_float4(ex, ey, e2, 0.0f);
        }

        // Projection matrix for this p (uniform -> scalar loads).
        const float* M = pm + p * 12;
        const float m00 = M[0], m01 = M[1], m02 = M[2],  m03 = M[3];
        const float m10 = M[4], m11 = M[5], m12 = M[6],  m13 = M[7];
        const float m20 = M[8], m21 = M[9], m22 = M[10], m23 = M[11];

        // Each thread owns 8 vertices (v = tid + i*256): project once.
        float px2[8], py2[8], v2[8], mn[8];
        #pragma unroll
        for (int i = 0; i < 8; i++) {
            const int v = tid + (i << 8);
            const float x = xs[((size_t)b * NV + v) * 3 + 0];
            const float y = xs[((size_t)b * NV + v) * 3 + 1];
            const float z = xs[((size_t)b * NV + v) * 3 + 2];
            const float r0 = m00 * x + m01 * y + m02 * z + m03;
            const float r1 = m10 * x + m11 * y + m12 * z + m13;
            const float r2 = m20 * x + m21 * y + m22 * z + m23;
            const float inv = 1.0f / r2;       // r2 ~ 2.0 by construction
            const float px = r0 * inv;
            const float py = r1 * inv;
            px2[i] = -2.0f * px;
            py2[i] = -2.0f * py;
            v2[i]  = px * px + py * py;        // folded out of the min, added back at end
            mn[i]  = 3.0e38f;
        }
        __syncthreads();

        // Hot loop: 128 edges x 8 vertices, 3 VALU/pair (2 fma + min).
        #pragma unroll 4
        for (int k = 0; k < ECHUNK; k++) {
            const float4 ed = eds[k];
            #pragma unroll
            for (int i = 0; i < 8; i++)
                mn[i] = fminf(mn[i], fmaf(py2[i], ed.y, fmaf(px2[i], ed.x, ed.z)));
        }

        // Plain coalesced stores of this chunk's partial mins.
        float* dst = minpart + ((size_t)(combo * NCHUNK + echunk)) * NV;
        #pragma unroll
        for (int i = 0; i < 8; i++)
            dst[tid + (i << 8)] = mn[i] + v2[i];
    } else {
        // Volume: one face per thread, partial sum per block (no atomics).
        const int j = bid - 512;           // 0..63
        const int b = j >> 4;
        const int f = ((j & 15) << 8) + tid;
        const int* fc = faces + ((size_t)b * NF + f) * 3;
        const int i0 = fc[0], i1 = fc[1], i2 = fc[2];
        const float* xb = xs + (size_t)b * NV * 3;
        const float ax = xb[i0 * 3 + 0], ay = xb[i0 * 3 + 1], az = xb[i0 * 3 + 2];
        const float bx = xb[i1 * 3 + 0], by = xb[i1 * 3 + 1], bz = xb[i1 * 3 + 2];
        const float cx = xb[i2 * 3 + 0], cy = xb[i2 * 3 + 1], cz = xb[i2 * 3 + 2];
        const float crx = ay * bz - az * by;
        const float cry = az * bx - ax * bz;
        const float crz = ax * by - ay * bx;
        float fv = (crx * cx + cry * cy + crz * cz) * (1.0f / 6.0f);

        #pragma unroll
        for (int off = 32; off > 0; off >>= 1) fv += __shfl_down(fv, off);
        const int lane = tid & 63, w = tid >> 6;
        if (lane == 0) red[w] = fv;
        __syncthreads();
        if (tid == 0) volpart[j] = red[0] + red[1] + red[2] + red[3];
    }
}

// K2: one block per (b,p) combo. Min over 16 chunks, masked mean over v.
__global__ __launch_bounds__(256) void fused_k2(
    const float* __restrict__ minpart, const void* __restrict__ maskp,
    float* __restrict__ percombo)
{
    __shared__ float reds[4], redc[4];
    const int tid = threadIdx.x;
    const int lane = tid & 63, w = tid >> 6;
    const int combo = blockIdx.x;

    // Sniff boundary_mask dtype: int32 0/1 words are <=1; packed 1-byte bools
    // read as words exceed 1 with overwhelming probability over 16 words.
    const int* mi = (const int*)maskp;
    const unsigned char* mb = (const unsigned char*)maskp;
    bool as_int = true;
    #pragma unroll
    for (int k = 0; k < 16; k++)
        if (((const unsigned*)maskp)[k] > 1u) as_int = false;

    const float* base = minpart + (size_t)combo * NCHUNK * NV;
    float s = 0.0f, c = 0.0f;
    #pragma unroll
    for (int i = 0; i < 8; i++) {
        const int v = tid + (i << 8);
        float m = base[v];
        #pragma unroll
        for (int ch = 1; ch < NCHUNK; ch++)
            m = fminf(m, base[ch * NV + v]);
        const size_t mix = (size_t)combo * NV + v;
        const float msk = as_int ? (mi[mix] ? 1.0f : 0.0f)
                                 : (mb[mix] ? 1.0f : 0.0f);
        s += m * msk;
        c += msk;
    }
    #pragma unroll
    for (int off = 32; off > 0; off >>= 1) {
        s += __shfl_down(s, off);
        c += __shfl_down(c, off);
    }
    if (lane == 0) { reds[w] = s; redc[w] = c; }
    __syncthreads();
    if (tid == 0) {
        const float S = reds[0] + reds[1] + reds[2] + reds[3];
        const float C = redc[0] + redc[1] + redc[2] + redc[3];
        percombo[combo] = S / fmaxf(C, 1.0f);
    }
}

// K3: finalize both outputs (1 tiny block).
__global__ __launch_bounds__(64) void fused_k3(
    const float* __restrict__ percombo, const float* __restrict__ volpart,
    const float* __restrict__ tv, float* __restrict__ out)
{
    const int b = threadIdx.x;
    if (b < NB) {
        float a = 0.0f;
        #pragma unroll
        for (int p = 0; p < NP; p++) a += percombo[b * NP + p];
        out[b] = a * (1.0f / NP);
        float vs = 0.0f;
        #pragma unroll
        for (int k = 0; k < 16; k++) vs += volpart[b * 16 + k];
        const float d = fabsf(vs) - tv[b];
        out[4 + b] = d * d;
    }
}

extern "C" void kernel_launch(void* const* d_in, const int* in_sizes, int n_in,
                              void* d_out, int out_size, void* d_ws, size_t ws_size,
                              hipStream_t stream)
{
    const float* xs       = (const float*)d_in[0];
    const float* pm       = (const float*)d_in[1];
    const float* edgemaps = (const float*)d_in[2];
    const int*   elen     = (const int*)d_in[3];
    const void*  mask     = d_in[4];
    const int*   faces    = (const int*)d_in[5];
    const float* tv       = (const float*)d_in[6];
    float* out = (float*)d_out;

    float* minpart  = (float*)d_ws;                 // 4 MB partial mins
    float* volpart  = minpart + MINPART_FLOATS;     // 64 floats
    float* percombo = volpart + 64;                 // 32 floats

    fused_k1<<<dim3(576), dim3(256), 0, stream>>>(xs, pm, edgemaps, elen, faces, minpart, volpart);
    fused_k2<<<dim3(NCOMBO), dim3(256), 0, stream>>>(minpart, mask, percombo);
    fused_k3<<<dim3(1), dim3(64), 0, stream>>>(percombo, volpart, tv, out);
}